// Round 9
// baseline (185.944 us; speedup 1.0000x reference)
//
#include <hip/hip_runtime.h>

// PCLLoss: C=256 classes, N=64 samples/class, D=1024.
// loss = mean_i [ sum_c ( log(eps + S_{i,c}) - pred[i,c] ) ]
// pred = Mv Mv^T, true = Mt Mt^T, Mv/Mt = per-class means of L2-normalized
// rows; S_{i,c} = sum_j exp(pred[i,j]) over j ranked at-or-after c in a
// stable descending sort of true[i,:]  (computed sort-free via an O(C) scan).
//
// R9: max-MLP k1. R8 (nt loads) confirmed L2-alloc churn was real: k1
// 46.7->~40 us. Residual theory: R6's round structure only keeps 4
// prefetched float4/wave in flight across each butterfly+barrier. Now:
// PARTS=8, 4096 blocks, 8 rows/block in ONE round -- each wave issues all
// 8 nt loads with zero dependencies (8 KB/wave in flight, ~128 KB/CU at
// 4 blocks/CU), single barrier, LDS-only accumulate. k3a sums 8 parts.

#define CC 256
#define NN 64
#define DD 1024
#define PARTS 8
#define TK 128   // K-slice for gram split-K

typedef float v4f __attribute__((ext_vector_type(4)));
__device__ __forceinline__ float4 ntload4(const float* p) {
    v4f v = __builtin_nontemporal_load((const v4f*)p);
    return make_float4(v.x, v.y, v.z, v.w);
}

// ---------------- K1: normalize + partial class sums ------------------
// grid = 2*CC*PARTS = 4096 blocks x 256 thr. Block (t,c,p): 8 rows; wave w
// owns rows 2w,2w+1 (all 8 nt loads issued back-to-back), stages to LDS
// while computing 2 interleaved sums-of-squares; one barrier; all threads
// scale-accumulate their 4 columns over the 8 rows from LDS.
__global__ __launch_bounds__(256) void k1_partial(
    const float* __restrict__ emb, const float* __restrict__ feat,
    float* __restrict__ parts /* [2][CC][PARTS][DD] */, float* __restrict__ out)
{
    if (blockIdx.x == 0 && threadIdx.x == 0) out[0] = 0.f;  // for k3b atomics

    int b = blockIdx.x;
    int t = b >> 11;              // tensor
    int c = (b >> 3) & 255;       // class
    int p = b & 7;                // part (8 rows)
    const float* src = (t == 0 ? emb : feat) + ((size_t)c * NN + p * 8) * DD;
    int wave = threadIdx.x >> 6, lane = threadIdx.x & 63;
    int col = threadIdx.x * 4;    // this thread's 4 output columns

    __shared__ float sv[8][DD];   // 32 KB -> 4 blocks/CU
    __shared__ float sinv[8];

    // all 8 independent nt loads issued before any use
    float4 v[2][4];
    #pragma unroll
    for (int j = 0; j < 2; ++j) {
        const float* row = src + (size_t)(wave * 2 + j) * DD;
        #pragma unroll
        for (int k = 0; k < 4; ++k)
            v[j][k] = ntload4(row + k * 256 + lane * 4);
    }

    // stage to LDS + local sums of squares (regs die here)
    float ss[2];
    #pragma unroll
    for (int j = 0; j < 2; ++j) {
        int row = wave * 2 + j;
        ss[j] = 0.f;
        #pragma unroll
        for (int k = 0; k < 4; ++k) {
            *(float4*)&sv[row][k * 256 + lane * 4] = v[j][k];
            ss[j] += v[j][k].x * v[j][k].x + v[j][k].y * v[j][k].y +
                     v[j][k].z * v[j][k].z + v[j][k].w * v[j][k].w;
        }
    }
    // two interleaved butterflies
    #pragma unroll
    for (int m = 32; m >= 1; m >>= 1) {
        ss[0] += __shfl_xor(ss[0], m, 64);
        ss[1] += __shfl_xor(ss[1], m, 64);
    }
    if (lane == 0) {
        sinv[wave * 2 + 0] = 1.0f / fmaxf(sqrtf(ss[0]), 1e-12f);  // F.normalize eps
        sinv[wave * 2 + 1] = 1.0f / fmaxf(sqrtf(ss[1]), 1e-12f);
    }
    __syncthreads();  // the only barrier

    // accumulate own columns over 8 rows (LDS b128 + broadcast scalars)
    float4 acc = make_float4(0.f, 0.f, 0.f, 0.f);
    #pragma unroll
    for (int row = 0; row < 8; ++row) {
        float iv = sinv[row];
        float4 u = *(float4*)&sv[row][col];
        acc.x += u.x * iv; acc.y += u.y * iv;
        acc.z += u.z * iv; acc.w += u.w * iv;
    }
    *(float4*)(parts + (((size_t)t * CC + c) * PARTS + p) * DD + col) = acc;
}

// ---------------- K3a: split-K tiled Gram partials (k2 fused) ---------
// grid = 2 tensors * 16 tiles(64x64) * 8 K-splits = 256 blocks, 256 thr.
// Stages directly from parts: mean = (sum of 8 parts) / N at load time.
__global__ __launch_bounds__(256) void k3a_gram(
    const float* __restrict__ parts, float* __restrict__ gpart /* [2][8][CC][CC] */)
{
    __shared__ float As[64][132];
    __shared__ float Bs[TK][68];

    int b = blockIdx.x;
    int t = b >> 7;
    int r = b & 127;
    int ks = r >> 4;
    int ti = (r >> 2) & 3, tj = r & 3;
    int i0 = ti * 64, j0 = tj * 64, k0 = ks * TK;
    const float invN = 1.0f / (float)NN;

    for (int f = threadIdx.x; f < 64 * 32; f += 256) {
        int row = f >> 5, c4 = f & 31;
        const float* P = parts + ((size_t)(t * CC + i0 + row) * PARTS) * DD + k0 + c4 * 4;
        float4 s = make_float4(0.f, 0.f, 0.f, 0.f);
        #pragma unroll
        for (int q = 0; q < PARTS; ++q) {
            float4 x = *(const float4*)(P + (size_t)q * DD);
            s.x += x.x; s.y += x.y; s.z += x.z; s.w += x.w;
        }
        s.x *= invN; s.y *= invN; s.z *= invN; s.w *= invN;
        *(float4*)&As[row][c4 * 4] = s;
    }
    for (int f = threadIdx.x; f < 64 * 32; f += 256) {
        int row = f >> 5, c4 = f & 31;
        const float* P = parts + ((size_t)(t * CC + j0 + row) * PARTS) * DD + k0 + c4 * 4;
        float4 s = make_float4(0.f, 0.f, 0.f, 0.f);
        #pragma unroll
        for (int q = 0; q < PARTS; ++q) {
            float4 x = *(const float4*)(P + (size_t)q * DD);
            s.x += x.x; s.y += x.y; s.z += x.z; s.w += x.w;
        }
        Bs[c4 * 4 + 0][row] = s.x * invN;
        Bs[c4 * 4 + 1][row] = s.y * invN;
        Bs[c4 * 4 + 2][row] = s.z * invN;
        Bs[c4 * 4 + 3][row] = s.w * invN;
    }
    __syncthreads();

    int tr = threadIdx.x >> 4, tc = threadIdx.x & 15;
    float acc[4][4] = {};
    #pragma unroll 4
    for (int kk = 0; kk < TK; kk += 4) {
        float4 a[4], bb[4];
        #pragma unroll
        for (int q = 0; q < 4; ++q) a[q] = *(float4*)&As[tr * 4 + q][kk];
        #pragma unroll
        for (int kq = 0; kq < 4; ++kq) bb[kq] = *(float4*)&Bs[kk + kq][tc * 4];
        #pragma unroll
        for (int q = 0; q < 4; ++q) {
            acc[q][0] += a[q].x * bb[0].x + a[q].y * bb[1].x + a[q].z * bb[2].x + a[q].w * bb[3].x;
            acc[q][1] += a[q].x * bb[0].y + a[q].y * bb[1].y + a[q].z * bb[2].y + a[q].w * bb[3].y;
            acc[q][2] += a[q].x * bb[0].z + a[q].y * bb[1].z + a[q].z * bb[2].z + a[q].w * bb[3].z;
            acc[q][3] += a[q].x * bb[0].w + a[q].y * bb[1].w + a[q].z * bb[2].w + a[q].w * bb[3].w;
        }
    }

    float* G = gpart + (((size_t)(t * 8 + ks) * CC) + i0 + tr * 4) * CC + j0 + tc * 4;
    #pragma unroll
    for (int q = 0; q < 4; ++q)
        *(float4*)(G + (size_t)q * CC) =
            make_float4(acc[q][0], acc[q][1], acc[q][2], acc[q][3]);
}

// ---------------- K3b: reduce partials + ListMLE + final mean ---------
// grid = CC blocks; one atomicAdd per block into out (zeroed by k1).
__global__ __launch_bounds__(256) void k3b_listmle(
    const float* __restrict__ gpart, float* __restrict__ out)
{
    int i = blockIdx.x, c = threadIdx.x;
    float dp = 0.f, dt = 0.f;
    #pragma unroll
    for (int ks = 0; ks < 8; ++ks) {
        dp += gpart[((size_t)ks * CC + i) * CC + c];
        dt += gpart[((size_t)(8 + ks) * CC + i) * CC + c];
    }

    __shared__ float s_true[CC];
    __shared__ float s_pexp[CC];
    s_true[c] = dt;
    s_pexp[c] = expf(dp);
    __syncthreads();

    // S = sum exp(pred_j) over j ranked at-or-after c (stable desc by true)
    float S = 0.f;
    for (int j = 0; j < CC; ++j) {
        float tj = s_true[j];
        bool take = (tj < dt) || (tj == dt && j >= c);
        S += take ? s_pexp[j] : 0.f;
    }
    float contrib = logf(S + 1e-10f) - dp;

    #pragma unroll
    for (int m = 32; m >= 1; m >>= 1)
        contrib += __shfl_xor(contrib, m, 64);
    __shared__ float s_red[4];
    if ((c & 63) == 0) s_red[c >> 6] = contrib;
    __syncthreads();
    if (c == 0)
        atomicAdd(out, (s_red[0] + s_red[1] + s_red[2] + s_red[3]) * (1.0f / (float)CC));
}

extern "C" void kernel_launch(void* const* d_in, const int* in_sizes, int n_in,
                              void* d_out, int out_size, void* d_ws, size_t ws_size,
                              hipStream_t stream) {
    const float* emb  = (const float*)d_in[0];
    const float* feat = (const float*)d_in[1];
    float* ws = (float*)d_ws;
    float* parts = ws;                                  // 2*CC*PARTS*DD = 16 MiB
    float* gpart = parts + (size_t)2 * CC * PARTS * DD; // 2*8*CC*CC = 4 MiB

    k1_partial <<<2 * CC * PARTS, 256, 0, stream>>>(emb, feat, parts, (float*)d_out);
    k3a_gram   <<<256, 256, 0, stream>>>(parts, gpart);
    k3b_listmle<<<CC, 256, 0, stream>>>(gpart, (float*)d_out);
}